// Round 1
// baseline (996.605 us; speedup 1.0000x reference)
//
#include <hip/hip_runtime.h>
#include <hip/hip_bf16.h>

// ---------------------------------------------------------------------------
// GIN forward: 2x GINConv(sum-agg -> Linear+ReLU -> Linear) with outer ReLU,
// global mean pool per graph (batch sorted), FC to scalar per graph.
// ---------------------------------------------------------------------------

#define NODES 200000
#define EDGES 200000
#define GRAPHS 2048

// Scatter-add: agg[dst] += feat[src], F floats per row, float4 chunks.
template<int F>
__global__ __launch_bounds__(256) void scatter_add_k(
    const float* __restrict__ feat, const int* __restrict__ ei,
    float* __restrict__ agg, int E)
{
    const int CH = F / 4;
    int tid = blockIdx.x * blockDim.x + threadIdx.x;
    int total = E * CH;
    if (tid >= total) return;
    int e = tid / CH;
    int c = tid - e * CH;
    int s = ei[e];         // source node (row 0)
    int d = ei[E + e];     // target node (row 1)
    float4 v = *reinterpret_cast<const float4*>(feat + (size_t)s * F + c * 4);
    float* dst = agg + (size_t)d * F + c * 4;
    atomicAdd(dst + 0, v.x);
    atomicAdd(dst + 1, v.y);
    atomicAdd(dst + 2, v.z);
    atomicAdd(dst + 3, v.w);
}

// out[row, 0:64] = relu( (A [+ A2]) @ W + bias ),  A: [N,K], W: [K,64]
// Block: 256 threads = 16 rows x 16 col-groups; each thread does 4 cols.
template<int K, bool ADD>
__global__ __launch_bounds__(256) void gemm_bias_relu_k(
    const float* __restrict__ A, const float* __restrict__ A2,
    const float* __restrict__ W, const float* __restrict__ bias,
    float* __restrict__ out, int N)
{
    __shared__ float Ws[K * 64];
    __shared__ float bs[64];
    int tid = threadIdx.x;
    for (int i = tid; i < K * 64; i += 256) Ws[i] = W[i];
    if (tid < 64) bs[tid] = bias[tid];
    __syncthreads();

    int tx = tid & 15;   // col group: cols tx, tx+16, tx+32, tx+48
    int ty = tid >> 4;   // row within block
    int row = blockIdx.x * 16 + ty;
    if (row >= N) return;

    const float* Ar = A + (size_t)row * K;
    const float* A2r = A2 + (size_t)row * K;

    float acc0 = bs[tx], acc1 = bs[tx + 16], acc2 = bs[tx + 32], acc3 = bs[tx + 48];

    #pragma unroll 4
    for (int k = 0; k < K; k += 4) {
        float4 a = *reinterpret_cast<const float4*>(Ar + k);
        if (ADD) {
            float4 b = *reinterpret_cast<const float4*>(A2r + k);
            a.x += b.x; a.y += b.y; a.z += b.z; a.w += b.w;
        }
        float av[4] = {a.x, a.y, a.z, a.w};
        #pragma unroll
        for (int j = 0; j < 4; ++j) {
            const float* wr = Ws + (k + j) * 64;
            acc0 = fmaf(av[j], wr[tx],      acc0);
            acc1 = fmaf(av[j], wr[tx + 16], acc1);
            acc2 = fmaf(av[j], wr[tx + 32], acc2);
            acc3 = fmaf(av[j], wr[tx + 48], acc3);
        }
    }

    float* orow = out + (size_t)row * 64;
    orow[tx]      = fmaxf(acc0, 0.f);
    orow[tx + 16] = fmaxf(acc1, 0.f);
    orow[tx + 32] = fmaxf(acc2, 0.f);
    orow[tx + 48] = fmaxf(acc3, 0.f);
}

// One block per graph. batch is sorted; binary-search the segment, mean over
// nodes, dot with fcW, add fcb.
__global__ __launch_bounds__(256) void pool_fc_k(
    const float* __restrict__ h, const int* __restrict__ batch,
    const float* __restrict__ fcW, const float* __restrict__ fcb,
    float* __restrict__ out, int N)
{
    int g = blockIdx.x;
    __shared__ int seg[2];
    if (threadIdx.x == 0) {
        int lo = 0, hi = N;
        while (lo < hi) { int m = (lo + hi) >> 1; if (batch[m] < g) lo = m + 1; else hi = m; }
        seg[0] = lo;
        hi = N;  // lower bound for g+1, start from seg[0]
        while (lo < hi) { int m = (lo + hi) >> 1; if (batch[m] < g + 1) lo = m + 1; else hi = m; }
        seg[1] = lo;
    }
    __syncthreads();
    int start = seg[0], end = seg[1];

    int tx = threadIdx.x & 63;   // feature
    int ty = threadIdx.x >> 6;   // 0..3 node-stripe
    float acc = 0.f;
    for (int n = start + ty; n < end; n += 4)
        acc += h[(size_t)n * 64 + tx];

    __shared__ float red[4][64];
    red[ty][tx] = acc;
    __syncthreads();
    if (ty == 0) {
        float s = red[0][tx] + red[1][tx] + red[2][tx] + red[3][tx];
        float cnt = fmaxf((float)(end - start), 1.f);
        float v = (s / cnt) * fcW[tx];
        #pragma unroll
        for (int off = 32; off >= 1; off >>= 1) v += __shfl_down(v, off);
        if (tx == 0) out[g] = v + fcb[0];
    }
}

extern "C" void kernel_launch(void* const* d_in, const int* in_sizes, int n_in,
                              void* d_out, int out_size, void* d_ws, size_t ws_size,
                              hipStream_t stream)
{
    const float* x    = (const float*)d_in[0];
    const int*   ei   = (const int*)d_in[1];   // [2, E]
    const int*   batch= (const int*)d_in[2];   // [N], sorted
    const float* W1a  = (const float*)d_in[3];
    const float* b1a  = (const float*)d_in[4];
    const float* W1b  = (const float*)d_in[5];
    const float* b1b  = (const float*)d_in[6];
    const float* W2a  = (const float*)d_in[7];
    const float* b2a  = (const float*)d_in[8];
    const float* W2b  = (const float*)d_in[9];
    const float* b2b  = (const float*)d_in[10];
    const float* fcW  = (const float*)d_in[11];
    const float* fcb  = (const float*)d_in[12];
    float* out = (float*)d_out;

    const int N = NODES, E = EDGES, G = GRAPHS;
    char* ws = (char*)d_ws;
    const size_t szA = (size_t)N * 128 * sizeof(float);  // 102.4 MB
    const size_t szH = (size_t)N * 64 * sizeof(float);   // 51.2 MB

    float* agg1 = (float*)ws;                  // [0, 102.4MB)
    float* z    = (float*)(ws + szA);          // [102.4, 153.6) z1 then z2
    float* h1   = (float*)(ws + szA + szH);    // [153.6, 204.8)
    float* agg2 = agg1;                        // reuse [0, 51.2)
    float* h2   = (float*)(ws + szH);          // reuse [51.2, 102.4)

    // ---- layer 1 ----
    hipMemsetAsync(agg1, 0, szA, stream);
    scatter_add_k<128><<<(E * 32 + 255) / 256, 256, 0, stream>>>(x, ei, agg1, E);
    gemm_bias_relu_k<128, true ><<<(N + 15) / 16, 256, 0, stream>>>(x, agg1, W1a, b1a, z, N);
    gemm_bias_relu_k<64,  false><<<(N + 15) / 16, 256, 0, stream>>>(z, nullptr, W1b, b1b, h1, N);

    // ---- layer 2 ----
    hipMemsetAsync(agg2, 0, szH, stream);
    scatter_add_k<64><<<(E * 16 + 255) / 256, 256, 0, stream>>>(h1, ei, agg2, E);
    gemm_bias_relu_k<64, true ><<<(N + 15) / 16, 256, 0, stream>>>(h1, agg2, W2a, b2a, z, N);
    gemm_bias_relu_k<64, false><<<(N + 15) / 16, 256, 0, stream>>>(z, nullptr, W2b, b2b, h2, N);

    // ---- pool + fc ----
    pool_fc_k<<<G, 256, 0, stream>>>(h2, batch, fcW, fcb, out, N);
}

// Round 2
// 391.749 us; speedup vs baseline: 2.5440x; 2.5440x over previous
//
#include <hip/hip_runtime.h>
#include <hip/hip_bf16.h>

// ---------------------------------------------------------------------------
// GIN forward, restructured:
//   (x+agg)@W == x@W + scatter(x@W)  -> aggregate AFTER the first GEMM (64-wide)
//   scatter-add replaced by CSR build (once) + gather aggregation (no fp atomics)
// Pipeline:
//   CSR build from edge_index (dst-sorted adjacency)
//   y1 = x @ W1a
//   zin1 = relu(y1 + gather-sum(y1) + b1a)
//   h1 = relu(zin1 @ W1b + b1b)
//   y2 = h1 @ W2a
//   zin2 = relu(y2 + gather-sum(y2) + b2a)
//   h2 = relu(zin2 @ W2b + b2b)
//   out[g] = mean-pool(h2 over graph g) . fcW + fcb
// ---------------------------------------------------------------------------

#define NODES 200000
#define EDGES 200000
#define GRAPHS 2048
#define NB_SCAN 782   // ceil(NODES/256)

// ---------------- CSR build ----------------
__global__ __launch_bounds__(256) void count_k(
    const int* __restrict__ ei, int* __restrict__ cnt, int E)
{
    int e = blockIdx.x * 256 + threadIdx.x;
    if (e < E) atomicAdd(&cnt[ei[E + e]], 1);
}

// per-block exclusive scan of 256 ints; block totals to bsum
__global__ __launch_bounds__(256) void scan1_k(
    const int* __restrict__ cnt, int* __restrict__ excl,
    int* __restrict__ bsum, int N)
{
    __shared__ int sh[256];
    int tid = threadIdx.x;
    int i = blockIdx.x * 256 + tid;
    int v = (i < N) ? cnt[i] : 0;
    sh[tid] = v;
    __syncthreads();
    for (int off = 1; off < 256; off <<= 1) {
        int t = (tid >= off) ? sh[tid - off] : 0;
        __syncthreads();
        sh[tid] += t;
        __syncthreads();
    }
    if (i < N) excl[i] = sh[tid] - v;
    if (tid == 255) bsum[blockIdx.x] = sh[255];
}

// single-block exclusive scan of the block totals
__global__ __launch_bounds__(1024) void scan2_k(int* __restrict__ bsum, int NB)
{
    __shared__ int sh[1024];
    int tid = threadIdx.x;
    int v = (tid < NB) ? bsum[tid] : 0;
    sh[tid] = v;
    __syncthreads();
    for (int off = 1; off < 1024; off <<= 1) {
        int t = (tid >= off) ? sh[tid - off] : 0;
        __syncthreads();
        sh[tid] += t;
        __syncthreads();
    }
    if (tid < NB) bsum[tid] = sh[tid] - v;
}

__global__ __launch_bounds__(256) void scan3_k(
    int* __restrict__ rowptr, const int* __restrict__ bsum,
    int* __restrict__ cursor, int N, int E)
{
    int i = blockIdx.x * 256 + threadIdx.x;
    if (i < N) {
        int v = rowptr[i] + bsum[blockIdx.x];
        rowptr[i] = v;
        cursor[i] = v;
    }
    if (i == 0) rowptr[N] = E;
}

__global__ __launch_bounds__(256) void fill_k(
    const int* __restrict__ ei, int* __restrict__ cursor,
    int* __restrict__ srcs, int E)
{
    int e = blockIdx.x * 256 + threadIdx.x;
    if (e < E) {
        int d = ei[E + e];
        int p = atomicAdd(&cursor[d], 1);
        srcs[p] = ei[e];
    }
}

// ---------------- GEMM: out[N,64] = opt_relu(A[N,K] @ W[K,64] + opt_bias) ----
// 64x64 tile per block, 256 threads, each 4 rows x 4 cols.
template<int K, bool BIAS, bool RELU>
__global__ __launch_bounds__(256) void gemm64_k(
    const float* __restrict__ A, const float* __restrict__ W,
    const float* __restrict__ bias, float* __restrict__ out, int N)
{
    constexpr int KC = 32;
    __shared__ float Ws[K * 64];
    __shared__ float As[64 * 33];   // +1 pad: A-read banks vary with row

    const int tid = threadIdx.x;
    const int row0 = blockIdx.x * 64;

    // stage full W
    for (int i = tid; i < K * 16; i += 256)
        reinterpret_cast<float4*>(Ws)[i] = reinterpret_cast<const float4*>(W)[i];

    const int tx4 = (tid & 15) * 4;   // output cols tx4..tx4+3
    const int ty4 = (tid >> 4) * 4;   // output rows ty4..ty4+3 (within tile)

    float acc[4][4];
    if (BIAS) {
        float4 b4 = *reinterpret_cast<const float4*>(bias + tx4);
        #pragma unroll
        for (int r = 0; r < 4; ++r) {
            acc[r][0] = b4.x; acc[r][1] = b4.y; acc[r][2] = b4.z; acc[r][3] = b4.w;
        }
    } else {
        #pragma unroll
        for (int r = 0; r < 4; ++r)
            #pragma unroll
            for (int c = 0; c < 4; ++c) acc[r][c] = 0.f;
    }

    const int sr = tid >> 3;        // staging row 0..31 (and +32)
    const int sq = (tid & 7) * 4;   // staging col group within chunk

    for (int kc = 0; kc < K; kc += KC) {
        float4 v0 = *reinterpret_cast<const float4*>(A + (size_t)(row0 + sr) * K + kc + sq);
        float4 v1 = *reinterpret_cast<const float4*>(A + (size_t)(row0 + sr + 32) * K + kc + sq);
        __syncthreads();   // protect LDS from previous chunk's readers
        As[sr * 33 + sq + 0] = v0.x;
        As[sr * 33 + sq + 1] = v0.y;
        As[sr * 33 + sq + 2] = v0.z;
        As[sr * 33 + sq + 3] = v0.w;
        As[(sr + 32) * 33 + sq + 0] = v1.x;
        As[(sr + 32) * 33 + sq + 1] = v1.y;
        As[(sr + 32) * 33 + sq + 2] = v1.z;
        As[(sr + 32) * 33 + sq + 3] = v1.w;
        __syncthreads();

        #pragma unroll
        for (int k = 0; k < KC; ++k) {
            float4 w = *reinterpret_cast<const float4*>(&Ws[(kc + k) * 64 + tx4]);
            float a0 = As[(ty4 + 0) * 33 + k];
            float a1 = As[(ty4 + 1) * 33 + k];
            float a2 = As[(ty4 + 2) * 33 + k];
            float a3 = As[(ty4 + 3) * 33 + k];
            acc[0][0] = fmaf(a0, w.x, acc[0][0]);
            acc[0][1] = fmaf(a0, w.y, acc[0][1]);
            acc[0][2] = fmaf(a0, w.z, acc[0][2]);
            acc[0][3] = fmaf(a0, w.w, acc[0][3]);
            acc[1][0] = fmaf(a1, w.x, acc[1][0]);
            acc[1][1] = fmaf(a1, w.y, acc[1][1]);
            acc[1][2] = fmaf(a1, w.z, acc[1][2]);
            acc[1][3] = fmaf(a1, w.w, acc[1][3]);
            acc[2][0] = fmaf(a2, w.x, acc[2][0]);
            acc[2][1] = fmaf(a2, w.y, acc[2][1]);
            acc[2][2] = fmaf(a2, w.z, acc[2][2]);
            acc[2][3] = fmaf(a2, w.w, acc[2][3]);
            acc[3][0] = fmaf(a3, w.x, acc[3][0]);
            acc[3][1] = fmaf(a3, w.y, acc[3][1]);
            acc[3][2] = fmaf(a3, w.z, acc[3][2]);
            acc[3][3] = fmaf(a3, w.w, acc[3][3]);
        }
    }

    #pragma unroll
    for (int r = 0; r < 4; ++r) {
        float4 o;
        o.x = RELU ? fmaxf(acc[r][0], 0.f) : acc[r][0];
        o.y = RELU ? fmaxf(acc[r][1], 0.f) : acc[r][1];
        o.z = RELU ? fmaxf(acc[r][2], 0.f) : acc[r][2];
        o.w = RELU ? fmaxf(acc[r][3], 0.f) : acc[r][3];
        *reinterpret_cast<float4*>(out + (size_t)(row0 + ty4 + r) * 64 + tx4) = o;
    }
}

// ---------------- aggregation: zin[n] = relu(y[n] + sum_{s in N(n)} y[s] + b) ----
// 16 threads per node, one float4 each. Grid covers N*16 threads exactly.
__global__ __launch_bounds__(256) void agg_relu_k(
    const float* __restrict__ y, const int* __restrict__ rowptr,
    const int* __restrict__ srcs, const float* __restrict__ bias,
    float* __restrict__ zin, int N)
{
    int t = blockIdx.x * 256 + threadIdx.x;
    int node = t >> 4;
    if (node >= N) return;
    int c = (t & 15) * 4;

    int s0 = rowptr[node];
    int s1 = rowptr[node + 1];

    float4 acc = *reinterpret_cast<const float4*>(y + (size_t)node * 64 + c);
    float4 b4 = *reinterpret_cast<const float4*>(bias + c);
    acc.x += b4.x; acc.y += b4.y; acc.z += b4.z; acc.w += b4.w;

    for (int j = s0; j < s1; ++j) {
        int s = srcs[j];
        float4 v = *reinterpret_cast<const float4*>(y + (size_t)s * 64 + c);
        acc.x += v.x; acc.y += v.y; acc.z += v.z; acc.w += v.w;
    }

    float4 o;
    o.x = fmaxf(acc.x, 0.f);
    o.y = fmaxf(acc.y, 0.f);
    o.z = fmaxf(acc.z, 0.f);
    o.w = fmaxf(acc.w, 0.f);
    *reinterpret_cast<float4*>(zin + (size_t)node * 64 + c) = o;
}

// ---------------- pool + fc ----------------
__global__ __launch_bounds__(256) void pool_fc_k(
    const float* __restrict__ h, const int* __restrict__ batch,
    const float* __restrict__ fcW, const float* __restrict__ fcb,
    float* __restrict__ out, int N)
{
    int g = blockIdx.x;
    __shared__ int seg[2];
    if (threadIdx.x == 0) {
        int lo = 0, hi = N;
        while (lo < hi) { int m = (lo + hi) >> 1; if (batch[m] < g) lo = m + 1; else hi = m; }
        seg[0] = lo;
        hi = N;
        while (lo < hi) { int m = (lo + hi) >> 1; if (batch[m] < g + 1) lo = m + 1; else hi = m; }
        seg[1] = lo;
    }
    __syncthreads();
    int start = seg[0], end = seg[1];

    int tx = threadIdx.x & 63;
    int ty = threadIdx.x >> 6;
    float acc = 0.f;
    for (int n = start + ty; n < end; n += 4)
        acc += h[(size_t)n * 64 + tx];

    __shared__ float red[4][64];
    red[ty][tx] = acc;
    __syncthreads();
    if (ty == 0) {
        float s = red[0][tx] + red[1][tx] + red[2][tx] + red[3][tx];
        float cnt = fmaxf((float)(end - start), 1.f);
        float v = (s / cnt) * fcW[tx];
        #pragma unroll
        for (int off = 32; off >= 1; off >>= 1) v += __shfl_down(v, off);
        if (tx == 0) out[g] = v + fcb[0];
    }
}

extern "C" void kernel_launch(void* const* d_in, const int* in_sizes, int n_in,
                              void* d_out, int out_size, void* d_ws, size_t ws_size,
                              hipStream_t stream)
{
    const float* x     = (const float*)d_in[0];
    const int*   ei    = (const int*)d_in[1];   // [2, E]
    const int*   batch = (const int*)d_in[2];   // [N], sorted
    const float* W1a   = (const float*)d_in[3];
    const float* b1a   = (const float*)d_in[4];
    const float* W1b   = (const float*)d_in[5];
    const float* b1b   = (const float*)d_in[6];
    const float* W2a   = (const float*)d_in[7];
    const float* b2a   = (const float*)d_in[8];
    const float* W2b   = (const float*)d_in[9];
    const float* b2b   = (const float*)d_in[10];
    const float* fcW   = (const float*)d_in[11];
    const float* fcb   = (const float*)d_in[12];
    float* out = (float*)d_out;

    const int N = NODES, E = EDGES, G = GRAPHS;
    char* ws = (char*)d_ws;
    const size_t szH = (size_t)N * 64 * sizeof(float);   // 51.2 MB

    float* yBuf   = (float*)ws;                 // [0, 51.2)
    float* zinBuf = (float*)(ws + szH);         // [51.2, 102.4)
    float* hBuf   = (float*)(ws + 2 * szH);     // [102.4, 153.6)
    char*  csr    = ws + 3 * szH;
    int* cnt    = (int*)csr;            // N
    int* rowptr = cnt + NODES;          // N+1
    int* cursor = rowptr + NODES + 1;   // N
    int* srcs   = cursor + NODES;       // E
    int* bsum   = srcs + EDGES;         // NB_SCAN

    // ---- CSR build (dst-sorted adjacency), reused by both layers ----
    hipMemsetAsync(cnt, 0, (size_t)N * sizeof(int), stream);
    count_k<<<NB_SCAN, 256, 0, stream>>>(ei, cnt, E);
    scan1_k<<<NB_SCAN, 256, 0, stream>>>(cnt, rowptr, bsum, N);
    scan2_k<<<1, 1024, 0, stream>>>(bsum, NB_SCAN);
    scan3_k<<<NB_SCAN, 256, 0, stream>>>(rowptr, bsum, cursor, N, E);
    fill_k<<<NB_SCAN, 256, 0, stream>>>(ei, cursor, srcs, E);

    // ---- layer 1 ----
    gemm64_k<128, false, false><<<N / 64, 256, 0, stream>>>(x, W1a, nullptr, yBuf, N);
    agg_relu_k<<<N * 16 / 256, 256, 0, stream>>>(yBuf, rowptr, srcs, b1a, zinBuf, N);
    gemm64_k<64, true, true><<<N / 64, 256, 0, stream>>>(zinBuf, W1b, b1b, hBuf, N);

    // ---- layer 2 ----
    gemm64_k<64, false, false><<<N / 64, 256, 0, stream>>>(hBuf, W2a, nullptr, yBuf, N);
    agg_relu_k<<<N * 16 / 256, 256, 0, stream>>>(yBuf, rowptr, srcs, b2a, zinBuf, N);
    gemm64_k<64, true, true><<<N / 64, 256, 0, stream>>>(zinBuf, W2b, b2b, hBuf, N);

    // ---- pool + fc ----
    pool_fc_k<<<G, 256, 0, stream>>>(hBuf, batch, fcW, fcb, out, N);
}